// Round 7
// baseline (616.193 us; speedup 1.0000x reference)
//
#include <hip/hip_runtime.h>

typedef __attribute__((ext_vector_type(4))) float  f32x4;
typedef __attribute__((ext_vector_type(4))) float  float4v;
typedef __attribute__((ext_vector_type(4))) short  short4v;
typedef __attribute__((ext_vector_type(8))) short  short8v;
typedef __attribute__((ext_vector_type(8))) __bf16 bf16x8;

union Frag { short4v h[2]; short8v s8; };

__device__ __forceinline__ short f2bf(float f) {
  unsigned u = __builtin_bit_cast(unsigned, f);
  u = (u + 0x7fffu + ((u >> 16) & 1u)) >> 16;
  return (short)u;
}

__device__ __forceinline__ f32x4 mfma_bf16(const Frag& a, const Frag& b, f32x4 c) {
  return __builtin_amdgcn_mfma_f32_16x16x32_bf16(
      __builtin_bit_cast(bf16x8, a.s8), __builtin_bit_cast(bf16x8, b.s8), c, 0, 0, 0);
}

__device__ __forceinline__ int poscode(int i) {   // 11*(i/72) + (i/12)%6 + i%12
  int z = (i >= 72) ? 1 : 0;
  int rem = i - 72 * z;
  int y = rem / 12;
  return 11 * z + y + (rem - 12 * y);
}

// k-permute within a 32-chunk: slot order {r<16: (r/4)*8+r%4 ; r>=16: ((r-16)/4)*8+4+r%4}
// so one short8 at [lg*8] holds k = lg*4+{0..3}, lg*4+16+{0..3} (MFMA operand order).
__device__ __forceinline__ int kperm(int r) {
  return (r & 16) ? (((r - 16) >> 2) * 8 + 4 + (r & 3)) : ((r >> 2) * 8 + (r & 3));
}

// ---------------------------------------------------------------- K0: weights
// wtq [576][192] bf16, k-PERMUTED per 32-chunk; wto [192][192] bf16 plain col-major
__global__ __launch_bounds__(256) void k_transpose_w(
    const float* __restrict__ w_qkv, const float* __restrict__ w_o,
    short* __restrict__ wtq, short* __restrict__ wto) {
  int idx = blockIdx.x * 256 + threadIdx.x;
  if (idx < 110592) {
    int k = idx / 576, c = idx % 576;
    int kp = (k & ~31) + kperm(k & 31);
    wtq[c * 192 + kp] = f2bf(w_qkv[idx]);
  } else {
    int j = idx - 110592;
    int k = j / 192, c = j % 192;
    wto[c * 192 + k] = f2bf(w_o[j]);
  }
}

// ---------------------------------------------------------------- K0b: bias matrix
// bias6[h][144][144] fp32 = btab[(pos(m)-pos(n)+27)*6+h]
__global__ __launch_bounds__(256) void k_bias(
    const float* __restrict__ btab, float* __restrict__ bias6) {
  int idx = blockIdx.x * 256 + threadIdx.x;
  if (idx >= 124416) return;
  int h = idx / 20736, r = idx % 20736, m = r / 144, n = r % 144;
  bias6[idx] = btab[(poscode(m) - poscode(n) + 27) * 6 + h];
}

// ---------------------------------------------------------------- K1: QKV GEMM
// 64 rows x 288 cols per block; B-frags straight from global (L2-hot, one b128);
// A-frags one ds_read_b128 (k-permuted LDS). Q/K parts written d-PERMUTED.
__global__ __launch_bounds__(256, 3) void k_qkv(
    const float* __restrict__ x, const float* __restrict__ bqkv,
    const short* __restrict__ wtq, short* __restrict__ qkv) {
  __shared__ short a_lds[64][200];
  const int tid = threadIdx.x;
  const int lane = tid & 63, wv = tid >> 6;
  const int l15 = lane & 15, lg = lane >> 4;

  // swizzle: both col-halves of a row-group on the same XCD
  const int did = blockIdx.x;
  const int vid = (did & 7) * 576 + (did >> 3);
  const int row0 = (vid >> 1) * 64;
  const int col0 = (vid & 1) * 288;

#pragma unroll
  for (int i = 0; i < 12; ++i) {
    int flat = tid + 256 * i;               // 64 rows x 48 float4 chunks
    int r = flat / 48, c4 = flat % 48;
    float4v xv = *(const float4v*)&x[(size_t)(row0 + r) * 192 + c4 * 4];
    short4v sv = { f2bf(xv[0]), f2bf(xv[1]), f2bf(xv[2]), f2bf(xv[3]) };
    int k = c4 * 4, rr = k & 31;
    int pos = (k & ~31) + ((rr & 16) ? (((rr - 16) >> 2) * 8 + 4) : ((rr >> 2) * 8));
    *(short4v*)&a_lds[r][pos] = sv;
  }
  __syncthreads();

  f32x4 acc[18];
#pragma unroll
  for (int i = 0; i < 18; ++i) acc[i] = f32x4{0.f, 0.f, 0.f, 0.f};

  for (int kc = 0; kc < 6; ++kc) {
    Frag a;
    a.s8 = *(const short8v*)&a_lds[wv * 16 + l15][kc * 32 + lg * 8];
#pragma unroll
    for (int cf = 0; cf < 18; ++cf) {
      Frag bw;
      bw.s8 = *(const short8v*)&wtq[(col0 + cf * 16 + l15) * 192 + kc * 32 + lg * 8];
      acc[cf] = mfma_bf16(a, bw, acc[cf]);
    }
  }

#pragma unroll
  for (int cf = 0; cf < 18; ++cf) {
    int c = col0 + cf * 16 + l15;
    int part = c / 192, rem = c % 192;
    int h = rem >> 5, d = rem & 31;
    int dd = (part == 2) ? d : kperm(d);    // Q,K stored d-permuted; V plain
    float bias = bqkv[c];
    float scale = (part == 0) ? 0.17677669529663687f : 1.0f;
#pragma unroll
    for (int r = 0; r < 4; ++r) {
      int g = row0 + wv * 16 + lg * 4 + r;
      int b_ = g / 144, n = g - b_ * 144;
      float v = (acc[cf][r] + bias) * scale;
      qkv[(size_t)((part * 1024 + b_) * 6 + h) * 4608 + n * 32 + dd] = f2bf(v);
    }
  }
}

// ---------------------------------------------------------------- K2: attention
// One 256-thread block per (b, head-pair). K (d-permuted) + V^T (n-permuted,
// zero-padded tail) in LDS; mask rows in regs reused across the 2 heads;
// bias via float4 loads from precomputed bias6. LDS 44.5KB -> 3 blocks/CU.
__global__ __launch_bounds__(256, 3) void k_attn(
    const short* __restrict__ qkv, const float* __restrict__ mask,
    const float* __restrict__ bias6, float* __restrict__ out) {
  __shared__ short k_l[2][144][40];    // 23040 B, rows d-permuted 32 + pad 8
  __shared__ short vt[2][32][168];     // 21504 B, [d][n-permuted 160] + pad 8
  const int tid = threadIdx.x;
  const int lane = tid & 63, wv = tid >> 6;
  const int l15 = lane & 15, lg = lane >> 4;

  // swizzle: 6 blocks sharing a mask window ({b,b+512} x 3 head-pairs) -> same XCD
  const int did = blockIdx.x;
  const int vid = (did & 7) * 384 + (did >> 3);
  const int wm = vid / 6, r6 = vid - wm * 6;
  const int b = wm + (r6 >= 3 ? 512 : 0);
  const int hg = (r6 >= 3) ? r6 - 3 : r6;

  // ---- stage K (straight copy, already permuted): 2*144*4 short8 = 1152
  const size_t kbase = (size_t)((1024 + b) * 6 + hg * 2) * 4608;
#pragma unroll
  for (int i = 0; i < 5; ++i) {
    int flat = tid + 256 * i;
    if (flat < 1152) {
      int hh = flat / 576, r = flat % 576;
      int n = r >> 2, j8 = (r & 3) * 8;
      *(short8v*)&k_l[hh][n][j8] =
          *(const short8v*)&qkv[kbase + (size_t)hh * 4608 + n * 32 + j8];
    }
  }
  // ---- zero V^T tail slots (n_perm 128..159 where slot%8>=4): 2*32*16 = 1024
#pragma unroll
  for (int i = 0; i < 4; ++i) {
    int flat = tid + 256 * i;
    int hh = flat >> 9, r = flat & 511;
    int d = r >> 4, jj = r & 15;
    vt[hh][d][128 + (jj >> 2) * 8 + 4 + (jj & 3)] = 0;
  }
  // ---- stage V^T (transpose + n-permute): 2*144*8 short4 = 2304
  const size_t vbase = (size_t)((2048 + b) * 6 + hg * 2) * 4608;
#pragma unroll
  for (int i = 0; i < 9; ++i) {
    int flat = tid + 256 * i;
    int hh = flat / 1152, r = flat % 1152;
    int n = r >> 3, d4 = (r & 7) * 4;
    short4v vv = *(const short4v*)&qkv[vbase + (size_t)hh * 4608 + n * 32 + d4];
    int np = (n & ~31) + kperm(n & 31);
    vt[hh][d4 + 0][np] = vv[0];
    vt[hh][d4 + 1][np] = vv[1];
    vt[hh][d4 + 2][np] = vv[2];
    vt[hh][d4 + 3][np] = vv[3];
  }
  __syncthreads();    // only barrier; LDS read-only afterwards

  const float* maskw = &mask[(size_t)wm * 20736];
  const size_t qb = (size_t)(b * 6 + hg * 2) * 4608;

  for (int tt = wv; tt < 9; tt += 4) {
    const int q = tt * 16 + l15;
    f32x4 mrow[9];
#pragma unroll
    for (int cf = 0; cf < 9; ++cf)
      mrow[cf] = *(const float4v*)&maskw[q * 144 + cf * 16 + lg * 4];

    for (int hh = 0; hh < 2; ++hh) {
      Frag aq;                                     // Q row, d-permuted -> one b128
      aq.s8 = *(const short8v*)&qkv[qb + (size_t)hh * 4608 + q * 32 + lg * 8];

      f32x4 s[9];                 // s[cf][reg] = S[q][cf*16+lg*4+reg]
#pragma unroll
      for (int cf = 0; cf < 9; ++cf) {
        Frag bk;
        bk.s8 = *(const short8v*)&k_l[hh][cf * 16 + l15][lg * 8];
        s[cf] = mfma_bf16(bk, aq, f32x4{0.f, 0.f, 0.f, 0.f});
      }
      const float* brow = &bias6[(size_t)((hg * 2 + hh) * 144 + q) * 144];
#pragma unroll
      for (int cf = 0; cf < 9; ++cf) {
        float4v bv = *(const float4v*)&brow[cf * 16 + lg * 4];
        s[cf] += mrow[cf] + bv;
      }

      // in-register softmax over k (36 regs + lanes ^16, ^32)
      float mx = s[0][0];
#pragma unroll
      for (int cf = 0; cf < 9; ++cf)
#pragma unroll
        for (int reg = 0; reg < 4; ++reg) mx = fmaxf(mx, s[cf][reg]);
      mx = fmaxf(mx, __shfl_xor(mx, 16, 64));
      mx = fmaxf(mx, __shfl_xor(mx, 32, 64));
      float sum = 0.f;
#pragma unroll
      for (int cf = 0; cf < 9; ++cf)
#pragma unroll
        for (int reg = 0; reg < 4; ++reg) {
          float e = __expf(s[cf][reg] - mx);
          s[cf][reg] = e;
          sum += e;
        }
      sum += __shfl_xor(sum, 16, 64);
      sum += __shfl_xor(sum, 32, 64);
      const float rinv = 1.0f / sum;
#pragma unroll
      for (int cf = 0; cf < 9; ++cf)
#pragma unroll
        for (int reg = 0; reg < 4; ++reg) s[cf][reg] *= rinv;

      // PV: P fragments straight from s[]; V^T b128 reads (tail pre-zeroed)
      f32x4 o0 = {0.f, 0.f, 0.f, 0.f}, o1 = {0.f, 0.f, 0.f, 0.f};
#pragma unroll
      for (int kc = 0; kc < 5; ++kc) {
        Frag ap, b0, b1;
        ap.h[0] = short4v{ f2bf(s[2 * kc][0]), f2bf(s[2 * kc][1]),
                           f2bf(s[2 * kc][2]), f2bf(s[2 * kc][3]) };
        ap.h[1] = (kc < 4)
            ? short4v{ f2bf(s[2 * kc + 1][0]), f2bf(s[2 * kc + 1][1]),
                       f2bf(s[2 * kc + 1][2]), f2bf(s[2 * kc + 1][3]) }
            : short4v{0, 0, 0, 0};
        b0.s8 = *(const short8v*)&vt[hh][l15][kc * 32 + lg * 8];
        b1.s8 = *(const short8v*)&vt[hh][16 + l15][kc * 32 + lg * 8];
        o0 = mfma_bf16(ap, b0, o0);
        o1 = mfma_bf16(ap, b1, o1);
      }
#pragma unroll
      for (int rr = 0; rr < 4; ++rr) {
        const int m = tt * 16 + lg * 4 + rr;
        const size_t base = (size_t)(b * 144 + m) * 192 + (hg * 2 + hh) * 32;
        out[base + l15]      = o0[rr];
        out[base + 16 + l15] = o1[rr];
      }
    }
  }
}

// ---------------------------------------------------------------- K3: out proj (in-place)
__global__ __launch_bounds__(256, 2) void k_oproj(
    float* __restrict__ io, const float* __restrict__ bo,
    const short* __restrict__ wto) {
  __shared__ short a_lds[64][200];
  __shared__ short bT[192][40];
  const int tid = threadIdx.x;
  const int lane = tid & 63, wv = tid >> 6;
  const int l15 = lane & 15, lg = lane >> 4;
  const int row0 = blockIdx.x * 64;

#pragma unroll
  for (int i = 0; i < 12; ++i) {
    int flat = tid + 256 * i;
    int r = flat / 48, c4 = flat % 48;
    float4v xv = *(const float4v*)&io[(size_t)(row0 + r) * 192 + c4 * 4];
    short4v sv = { f2bf(xv[0]), f2bf(xv[1]), f2bf(xv[2]), f2bf(xv[3]) };
    *(short4v*)&a_lds[r][c4 * 4] = sv;
  }

  f32x4 acc[12];
#pragma unroll
  for (int i = 0; i < 12; ++i) acc[i] = f32x4{0.f, 0.f, 0.f, 0.f};

  for (int kc = 0; kc < 6; ++kc) {
    __syncthreads();
#pragma unroll
    for (int i = 0; i < 6; ++i) {
      int flat = tid + 256 * i;             // 192 cols x 8 quads = 1536
      int c = flat >> 3, kk = (flat & 7) << 2;
      *(short4v*)&bT[c][kk] = *(const short4v*)&wto[c * 192 + kc * 32 + kk];
    }
    __syncthreads();
    Frag a;
    a.h[0] = *(const short4v*)&a_lds[wv * 16 + l15][kc * 32 + lg * 4];
    a.h[1] = *(const short4v*)&a_lds[wv * 16 + l15][kc * 32 + lg * 4 + 16];
#pragma unroll
    for (int cf = 0; cf < 12; ++cf) {
      Frag bw;
      bw.h[0] = *(const short4v*)&bT[cf * 16 + l15][lg * 4];
      bw.h[1] = *(const short4v*)&bT[cf * 16 + l15][lg * 4 + 16];
      acc[cf] = mfma_bf16(a, bw, acc[cf]);
    }
  }

#pragma unroll
  for (int cf = 0; cf < 12; ++cf) {
    int c = cf * 16 + l15;
    float bias = bo[c];
#pragma unroll
    for (int r = 0; r < 4; ++r) {
      int g = row0 + wv * 16 + lg * 4 + r;
      io[(size_t)g * 192 + c] = acc[cf][r] + bias;
    }
  }
}

extern "C" void kernel_launch(void* const* d_in, const int* in_sizes, int n_in,
                              void* d_out, int out_size, void* d_ws, size_t ws_size,
                              hipStream_t stream) {
  const float* x    = (const float*)d_in[0];
  const float* mask = (const float*)d_in[1];
  const float* wqkv = (const float*)d_in[2];
  const float* bqkv = (const float*)d_in[3];
  const float* wo   = (const float*)d_in[4];
  const float* bo   = (const float*)d_in[5];
  const float* btab = (const float*)d_in[6];
  float* out = (float*)d_out;

  short* wtq   = (short*)d_ws;               //    110,592 shorts (permuted)
  short* wto   = wtq + 110592;               //     36,864 shorts
  short* qkv   = wto + 36864;                // 84,934,656 shorts (162 MB)
  float* bias6 = (float*)(qkv + 84934656);   //    124,416 floats (497 KB)

  k_transpose_w<<<576, 256, 0, stream>>>(wqkv, wo, wtq, wto);
  k_bias<<<486, 256, 0, stream>>>(btab, bias6);
  k_qkv<<<4608, 256, 0, stream>>>(x, bqkv, wtq, qkv);
  k_attn<<<3072, 256, 0, stream>>>(qkv, mask, bias6, out);
  k_oproj<<<2304, 256, 0, stream>>>(out, bo, wto);
}

// Round 8
// 267.776 us; speedup vs baseline: 2.3012x; 2.3012x over previous
//
#include <hip/hip_runtime.h>

typedef __attribute__((ext_vector_type(4))) float  f32x4;
typedef __attribute__((ext_vector_type(4))) float  float4v;
typedef __attribute__((ext_vector_type(4))) short  short4v;
typedef __attribute__((ext_vector_type(8))) short  short8v;
typedef __attribute__((ext_vector_type(8))) __bf16 bf16x8;

union Frag { short4v h[2]; short8v s8; };

__device__ __forceinline__ short f2bf(float f) {
  unsigned u = __builtin_bit_cast(unsigned, f);
  u = (u + 0x7fffu + ((u >> 16) & 1u)) >> 16;
  return (short)u;
}

__device__ __forceinline__ f32x4 mfma_bf16(const Frag& a, const Frag& b, f32x4 c) {
  return __builtin_amdgcn_mfma_f32_16x16x32_bf16(
      __builtin_bit_cast(bf16x8, a.s8), __builtin_bit_cast(bf16x8, b.s8), c, 0, 0, 0);
}

__device__ __forceinline__ int poscode(int i) {   // 11*(i/72) + (i/12)%6 + i%12
  int z = (i >= 72) ? 1 : 0;
  int rem = i - 72 * z;
  int y = rem / 12;
  return 11 * z + y + (rem - 12 * y);
}

// k-permute within a 32-chunk so one short8 at [lg*8] = MFMA operand order
// (k = lg*4+{0..3}, lg*4+16+{0..3}).
__device__ __forceinline__ int kperm(int r) {
  return (r & 16) ? (((r - 16) >> 2) * 8 + 4 + (r & 3)) : ((r >> 2) * 8 + (r & 3));
}

// ---------------------------------------------------------------- K0: weights
// wtq [576][192] bf16 k-PERMUTED per 32-chunk; wto [192][192] bf16 plain col-major
__global__ __launch_bounds__(256) void k_transpose_w(
    const float* __restrict__ w_qkv, const float* __restrict__ w_o,
    short* __restrict__ wtq, short* __restrict__ wto) {
  int idx = blockIdx.x * 256 + threadIdx.x;
  if (idx < 110592) {
    int k = idx / 576, c = idx % 576;
    int kp = (k & ~31) + kperm(k & 31);
    wtq[c * 192 + kp] = f2bf(w_qkv[idx]);
  } else {
    int j = idx - 110592;
    int k = j / 192, c = j % 192;
    wto[c * 192 + k] = f2bf(w_o[j]);
  }
}

// ---------------------------------------------------------------- K0b: bias matrix
// bias6[h][144][144] fp32 = btab[(pos(m)-pos(n)+27)*6+h]
__global__ __launch_bounds__(256) void k_bias(
    const float* __restrict__ btab, float* __restrict__ bias6) {
  int idx = blockIdx.x * 256 + threadIdx.x;
  if (idx >= 124416) return;
  int h = idx / 20736, r = idx % 20736, m = r / 144, n = r % 144;
  bias6[idx] = btab[(poscode(m) - poscode(n) + 27) * 6 + h];
}

// ---------------------------------------------------------------- K1: QKV GEMM
// Round-6 structure (64 rows x 576 cols, bT staged per kc) with single-b128
// operand reads (k-permuted LDS) and d-permuted Q/K output.
__global__ __launch_bounds__(256, 2) void k_qkv(
    const float* __restrict__ x, const float* __restrict__ bqkv,
    const short* __restrict__ wtq, short* __restrict__ qkv) {
  __shared__ short a_lds[64][200];   // k-permuted per 32-chunk; 400B rows (16B-aligned)
  __shared__ short bT[576][40];      // k-permuted 32-chunk; 80B rows
  const int tid = threadIdx.x;
  const int lane = tid & 63, wv = tid >> 6;
  const int l15 = lane & 15, lg = lane >> 4;
  const int row0 = blockIdx.x * 64;

#pragma unroll
  for (int i = 0; i < 12; ++i) {
    int flat = tid + 256 * i;               // 64 rows x 48 float4 chunks
    int r = flat / 48, c4 = flat % 48;
    float4v xv = *(const float4v*)&x[(size_t)(row0 + r) * 192 + c4 * 4];
    short4v sv = { f2bf(xv[0]), f2bf(xv[1]), f2bf(xv[2]), f2bf(xv[3]) };
    int k = c4 * 4, rr = k & 31;
    int pos = (k & ~31) + ((rr & 16) ? (((rr - 16) >> 2) * 8 + 4) : ((rr >> 2) * 8));
    *(short4v*)&a_lds[r][pos] = sv;
  }

  f32x4 acc[36];
#pragma unroll
  for (int i = 0; i < 36; ++i) acc[i] = f32x4{0.f, 0.f, 0.f, 0.f};

  for (int kc = 0; kc < 6; ++kc) {
    __syncthreads();
    // stage 576 cols x 32 shorts (permuted) = 2304 short8 copies = 9 x 256
#pragma unroll
    for (int i = 0; i < 9; ++i) {
      int flat = tid + 256 * i;
      int c = flat >> 2, j = flat & 3;
      *(short8v*)&bT[c][j * 8] = *(const short8v*)&wtq[c * 192 + kc * 32 + j * 8];
    }
    __syncthreads();
    Frag a;
    a.s8 = *(const short8v*)&a_lds[wv * 16 + l15][kc * 32 + lg * 8];
#pragma unroll
    for (int cf = 0; cf < 36; ++cf) {
      Frag bw;
      bw.s8 = *(const short8v*)&bT[cf * 16 + l15][lg * 8];
      acc[cf] = mfma_bf16(a, bw, acc[cf]);
    }
  }

#pragma unroll
  for (int cf = 0; cf < 36; ++cf) {
    int c = cf * 16 + l15;
    int part = c / 192, rem = c % 192;
    int h = rem >> 5, d = rem & 31;
    int dd = (part == 2) ? d : kperm(d);    // Q,K stored d-permuted; V plain
    float bias = bqkv[c];
    float scale = (part == 0) ? 0.17677669529663687f : 1.0f;
#pragma unroll
    for (int r = 0; r < 4; ++r) {
      int g = row0 + wv * 16 + lg * 4 + r;
      int b_ = g / 144, n = g - b_ * 144;
      float v = (acc[cf][r] + bias) * scale;
      qkv[(size_t)((part * 1024 + b_) * 6 + h) * 4608 + n * 32 + dd] = f2bf(v);
    }
  }
}

// ---------------------------------------------------------------- K2: attention
// Round-6 structure: one 512-thread block per b, ALL 6 heads' K/V^T in LDS,
// mask rows in regs reused across heads. Deltas: bias via precomputed bias6
// float4 loads; K straight-copied (d-permuted); Q one b128; V^T n-permuted.
__global__ __launch_bounds__(512, 2) void k_attn(
    const short* __restrict__ qkv, const float* __restrict__ mask,
    const float* __restrict__ bias6, float* __restrict__ out) {
  __shared__ short k_l[6][144][40];   // 69120 B, d-permuted rows
  __shared__ short vt[6][32][168];    // 64512 B, [d][n-permuted 160] (133.6 KB total)
  const int tid = threadIdx.x;
  const int lane = tid & 63, wv = tid >> 6;
  const int l15 = lane & 15, lg = lane >> 4;

  // pair-swizzle: (b, b+512) are 8 apart in launch order -> same XCD L2
  const int bid = blockIdx.x;
  const int b = ((bid >> 4) << 3) + (bid & 7) + (((bid >> 3) & 1) << 9);
  const int wm = b & 511;

  // ---- stage K all heads (straight s8 copy, already permuted): 3456 units
  const size_t kbase = (size_t)(1024 + b) * 6 * 4608;
#pragma unroll
  for (int i = 0; i < 7; ++i) {
    int flat = tid + 512 * i;
    if (flat < 3456) {
      int h = flat / 576, r = flat % 576;
      int n = r >> 2, j8 = (r & 3) * 8;
      *(short8v*)&k_l[h][n][j8] =
          *(const short8v*)&qkv[kbase + (size_t)h * 4608 + n * 32 + j8];
    }
  }
  // ---- zero V^T tail slots (n_perm 128..159, slot%8>=4): 6*32*16 = 3072
#pragma unroll
  for (int i = 0; i < 6; ++i) {
    int flat = tid + 512 * i;
    int h = flat / 512, r = flat & 511;
    int d = r >> 4, jj = r & 15;
    vt[h][d][128 + (jj >> 2) * 8 + 4 + (jj & 3)] = 0;
  }
  // ---- stage V^T (transpose + n-permute): 6*144*8 short4 = 6912 units
  const size_t vbase = (size_t)(2048 + b) * 6 * 4608;
#pragma unroll
  for (int i = 0; i < 14; ++i) {
    int flat = tid + 512 * i;
    if (flat < 6912) {
      int h = flat / 1152, r = flat % 1152;
      int n = r >> 3, d4 = (r & 7) * 4;
      short4v vv = *(const short4v*)&qkv[vbase + (size_t)h * 4608 + n * 32 + d4];
      int np = (n & ~31) + kperm(n & 31);
      vt[h][d4 + 0][np] = vv[0];
      vt[h][d4 + 1][np] = vv[1];
      vt[h][d4 + 2][np] = vv[2];
      vt[h][d4 + 3][np] = vv[3];
    }
  }
  __syncthreads();    // only barrier; LDS read-only afterwards

  const float* maskw = &mask[(size_t)wm * 20736];
  const size_t qb = (size_t)b * 6 * 4608;

  // units: wave w does (t=w, h=0..5); waves 0..5 additionally do (t=8, h=w)
  f32x4 mrow[9];
  int q = 0;
  for (int unit = 0; unit < 7; ++unit) {
    int t, h;
    if (unit < 6) { t = wv; h = unit; }
    else { if (wv >= 6) break; t = 8; h = wv; }
    if (unit == 0 || unit == 6) {
      q = t * 16 + l15;
#pragma unroll
      for (int cf = 0; cf < 9; ++cf)
        mrow[cf] = *(const float4v*)&maskw[q * 144 + cf * 16 + lg * 4];
    }

    Frag aq;                                 // Q row, d-permuted -> one b128
    aq.s8 = *(const short8v*)&qkv[qb + (size_t)h * 4608 + q * 32 + lg * 8];

    f32x4 s[9];                 // s[cf][reg] = S[q][cf*16+lg*4+reg]
#pragma unroll
    for (int cf = 0; cf < 9; ++cf) {
      Frag bk;
      bk.s8 = *(const short8v*)&k_l[h][cf * 16 + l15][lg * 8];
      s[cf] = mfma_bf16(bk, aq, f32x4{0.f, 0.f, 0.f, 0.f});
    }
    const float* brow = &bias6[(size_t)(h * 144 + q) * 144];
#pragma unroll
    for (int cf = 0; cf < 9; ++cf) {
      float4v bv = *(const float4v*)&brow[cf * 16 + lg * 4];
      s[cf] += mrow[cf] + bv;
    }

    // in-register softmax over k (36 regs + lanes ^16, ^32)
    float mx = s[0][0];
#pragma unroll
    for (int cf = 0; cf < 9; ++cf)
#pragma unroll
      for (int reg = 0; reg < 4; ++reg) mx = fmaxf(mx, s[cf][reg]);
    mx = fmaxf(mx, __shfl_xor(mx, 16, 64));
    mx = fmaxf(mx, __shfl_xor(mx, 32, 64));
    float sum = 0.f;
#pragma unroll
    for (int cf = 0; cf < 9; ++cf)
#pragma unroll
      for (int reg = 0; reg < 4; ++reg) {
        float e = __expf(s[cf][reg] - mx);
        s[cf][reg] = e;
        sum += e;
      }
    sum += __shfl_xor(sum, 16, 64);
    sum += __shfl_xor(sum, 32, 64);
    const float rinv = 1.0f / sum;
#pragma unroll
    for (int cf = 0; cf < 9; ++cf)
#pragma unroll
      for (int reg = 0; reg < 4; ++reg) s[cf][reg] *= rinv;

    // PV: P fragments straight from s[]; V^T single-b128 reads (tail zeroed)
    f32x4 o0 = {0.f, 0.f, 0.f, 0.f}, o1 = {0.f, 0.f, 0.f, 0.f};
#pragma unroll
    for (int kc = 0; kc < 5; ++kc) {
      Frag ap, b0, b1;
      ap.h[0] = short4v{ f2bf(s[2 * kc][0]), f2bf(s[2 * kc][1]),
                         f2bf(s[2 * kc][2]), f2bf(s[2 * kc][3]) };
      ap.h[1] = (kc < 4)
          ? short4v{ f2bf(s[2 * kc + 1][0]), f2bf(s[2 * kc + 1][1]),
                     f2bf(s[2 * kc + 1][2]), f2bf(s[2 * kc + 1][3]) }
          : short4v{0, 0, 0, 0};
      b0.s8 = *(const short8v*)&vt[h][l15][kc * 32 + lg * 8];
      b1.s8 = *(const short8v*)&vt[h][16 + l15][kc * 32 + lg * 8];
      o0 = mfma_bf16(ap, b0, o0);
      o1 = mfma_bf16(ap, b1, o1);
    }
#pragma unroll
    for (int rr = 0; rr < 4; ++rr) {
      const int m = t * 16 + lg * 4 + rr;
      const size_t base = (size_t)(b * 144 + m) * 192 + h * 32;
      out[base + l15]      = o0[rr];
      out[base + 16 + l15] = o1[rr];
    }
  }
}

// ---------------------------------------------------------------- K3: out proj (in-place)
__global__ __launch_bounds__(256, 2) void k_oproj(
    float* __restrict__ io, const float* __restrict__ bo,
    const short* __restrict__ wto) {
  __shared__ short a_lds[64][200];
  __shared__ short bT[192][40];
  const int tid = threadIdx.x;
  const int lane = tid & 63, wv = tid >> 6;
  const int l15 = lane & 15, lg = lane >> 4;
  const int row0 = blockIdx.x * 64;

#pragma unroll
  for (int i = 0; i < 12; ++i) {
    int flat = tid + 256 * i;
    int r = flat / 48, c4 = flat % 48;
    float4v xv = *(const float4v*)&io[(size_t)(row0 + r) * 192 + c4 * 4];
    short4v sv = { f2bf(xv[0]), f2bf(xv[1]), f2bf(xv[2]), f2bf(xv[3]) };
    *(short4v*)&a_lds[r][c4 * 4] = sv;
  }

  f32x4 acc[12];
#pragma unroll
  for (int i = 0; i < 12; ++i) acc[i] = f32x4{0.f, 0.f, 0.f, 0.f};

  for (int kc = 0; kc < 6; ++kc) {
    __syncthreads();
#pragma unroll
    for (int i = 0; i < 6; ++i) {
      int flat = tid + 256 * i;             // 192 cols x 8 quads = 1536
      int c = flat >> 3, kk = (flat & 7) << 2;
      *(short4v*)&bT[c][kk] = *(const short4v*)&wto[c * 192 + kc * 32 + kk];
    }
    __syncthreads();
    Frag a;
    a.h[0] = *(const short4v*)&a_lds[wv * 16 + l15][kc * 32 + lg * 4];
    a.h[1] = *(const short4v*)&a_lds[wv * 16 + l15][kc * 32 + lg * 4 + 16];
#pragma unroll
    for (int cf = 0; cf < 12; ++cf) {
      Frag bw;
      bw.h[0] = *(const short4v*)&bT[cf * 16 + l15][lg * 4];
      bw.h[1] = *(const short4v*)&bT[cf * 16 + l15][lg * 4 + 16];
      acc[cf] = mfma_bf16(a, bw, acc[cf]);
    }
  }

#pragma unroll
  for (int cf = 0; cf < 12; ++cf) {
    int c = cf * 16 + l15;
    float bias = bo[c];
#pragma unroll
    for (int r = 0; r < 4; ++r) {
      int g = row0 + wv * 16 + lg * 4 + r;
      io[(size_t)g * 192 + c] = acc[cf][r] + bias;
    }
  }
}

extern "C" void kernel_launch(void* const* d_in, const int* in_sizes, int n_in,
                              void* d_out, int out_size, void* d_ws, size_t ws_size,
                              hipStream_t stream) {
  const float* x    = (const float*)d_in[0];
  const float* mask = (const float*)d_in[1];
  const float* wqkv = (const float*)d_in[2];
  const float* bqkv = (const float*)d_in[3];
  const float* wo   = (const float*)d_in[4];
  const float* bo   = (const float*)d_in[5];
  const float* btab = (const float*)d_in[6];
  float* out = (float*)d_out;

  short* wtq   = (short*)d_ws;               //    110,592 shorts (k-permuted)
  short* wto   = wtq + 110592;               //     36,864 shorts
  short* qkv   = wto + 36864;                // 84,934,656 shorts (162 MB)
  float* bias6 = (float*)(qkv + 84934656);   //    124,416 floats (497 KB)

  k_transpose_w<<<576, 256, 0, stream>>>(wqkv, wo, wtq, wto);
  k_bias<<<486, 256, 0, stream>>>(btab, bias6);
  k_qkv<<<2304, 256, 0, stream>>>(x, bqkv, wtq, qkv);
  k_attn<<<1024, 512, 0, stream>>>(qkv, mask, bias6, out);
  k_oproj<<<2304, 256, 0, stream>>>(out, bo, wto);
}